// Round 17
// baseline (404.714 us; speedup 1.0000x reference)
//
#include <hip/hip_runtime.h>
#include <math.h>

typedef __attribute__((ext_vector_type(8))) short bf16x8;
typedef __attribute__((ext_vector_type(4))) float f32x4;

__device__ __forceinline__ unsigned short f2bf(float f) {
  unsigned int u = __float_as_uint(f);
  unsigned int r = (u + 0x7fffu + ((u >> 16) & 1u)) >> 16;
  return (unsigned short)r;
}
__device__ __forceinline__ unsigned int pack2bf(float a, float b) {
  return (unsigned int)f2bf(a) | ((unsigned int)f2bf(b) << 16);
}
__device__ __forceinline__ float bflo(unsigned int g) { return __uint_as_float(g << 16); }
__device__ __forceinline__ float bfhi(unsigned int g) { return __uint_as_float(g & 0xffff0000u); }

__device__ __forceinline__ void glds16(const void* gp, void* lp) {
  __builtin_amdgcn_global_load_lds(
      (const __attribute__((address_space(1))) void*)gp,
      (__attribute__((address_space(3))) void*)lp, 16, 0, 0);
}

// cos/sin(pi*j/16), j=0..15 — cover all in-lane FFT16/FFT32 twiddles
__device__ __constant__ float CW16[16] = {
  1.0f, 0.9807852804032304f, 0.9238795325112867f, 0.8314696123025452f,
  0.7071067811865476f, 0.5555702330196022f, 0.3826834323650898f, 0.19509032201612828f,
  0.0f, -0.19509032201612828f, -0.3826834323650898f, -0.5555702330196022f,
  -0.7071067811865476f, -0.8314696123025452f, -0.9238795325112867f, -0.9807852804032304f};
__device__ __constant__ float SW16[16] = {
  0.0f, 0.19509032201612828f, 0.3826834323650898f, 0.5555702330196022f,
  0.7071067811865476f, 0.8314696123025452f, 0.9238795325112867f, 0.9807852804032304f,
  1.0f, 0.9807852804032304f, 0.9238795325112867f, 0.8314696123025452f,
  0.7071067811865476f, 0.5555702330196022f, 0.3826834323650898f, 0.19509032201612828f};
__device__ __constant__ int BR5[32] = {
  0,16,8,24,4,20,12,28,2,18,10,26,6,22,14,30,
  1,17,9,25,5,21,13,29,3,19,11,27,7,23,15,31};

__device__ __forceinline__ int bitrev6(int l) {
  return ((l&1)<<5)|((l&2)<<3)|((l&4)<<1)|((l&8)>>1)|((l&16)>>3)|((l&32)>>5);
}

// hardware sin/cos: input in REVOLUTIONS (angle/2pi); all our args are in [0,1)
__device__ __forceinline__ float hsin(float rev) { return __builtin_amdgcn_sinf(rev); }
__device__ __forceinline__ float hcos(float rev) { return __builtin_amdgcn_cosf(rev); }

// ================= 2048-point cores (fallback path only) =================
__device__ __forceinline__ void fwd_core(float (&ur)[32], float (&ui)[32], const int lane) {
  #pragma unroll
  for (int s = 0; s < 6; ++s) {
    const int h = 32 >> s;
    const int j = lane & (h - 1);
    const float rev = (float)j * (0.5f / (float)h);
    const bool hi = (lane & h) != 0;
    const float c  = hi ? hcos(rev) : 1.0f;
    const float sv = hi ? hsin(rev) : 0.0f;
    const float sgn = hi ? -1.0f : 1.0f;
    #pragma unroll
    for (int r = 0; r < 32; ++r) {
      float pr = __shfl_xor(ur[r], h, 64);
      float pi = __shfl_xor(ui[r], h, 64);
      float tr = fmaf(sgn, ur[r], pr);
      float ti = fmaf(sgn, ui[r], pi);
      ur[r] = fmaf(ti, sv, tr * c);
      ui[r] = fmaf(-tr, sv, ti * c);
    }
  }
  const int kap = bitrev6(lane);
  #pragma unroll
  for (int j = 1; j < 32; ++j) {
    const float rev = (float)(j * kap) * (1.0f / 2048.0f);
    const float sn = hsin(rev), cs = hcos(rev);
    float t = ur[j] * cs + ui[j] * sn;
    ui[j] = ui[j] * cs - ur[j] * sn;
    ur[j] = t;
  }
  #pragma unroll
  for (int s = 0; s < 5; ++s) {
    const int h = 16 >> s;
    #pragma unroll
    for (int i = 0; i < 32; ++i) if (!(i & h)) {
      const int tw = (i & (h - 1)) * (16 / h);
      float dr = ur[i] - ur[i + h], di = ui[i] - ui[i + h];
      ur[i] += ur[i + h]; ui[i] += ui[i + h];
      ur[i + h] = dr * CW16[tw] + di * SW16[tw];
      ui[i + h] = di * CW16[tw] - dr * SW16[tw];
    }
  }
}

__device__ __forceinline__ void inv_core(float (&ur)[32], float (&ui)[32], const int lane) {
  const int kap = bitrev6(lane);
  #pragma unroll
  for (int s = 0; s < 5; ++s) {
    const int h = 1 << s;
    #pragma unroll
    for (int i = 0; i < 32; ++i) if (!(i & h)) {
      const int tw = (i & (h - 1)) * (16 / h);
      float tr2 = ur[i + h] * CW16[tw] - ui[i + h] * SW16[tw];
      float ti2 = ui[i + h] * CW16[tw] + ur[i + h] * SW16[tw];
      ur[i + h] = ur[i] - tr2; ui[i + h] = ui[i] - ti2;
      ur[i] += tr2; ui[i] += ti2;
    }
  }
  #pragma unroll
  for (int j = 1; j < 32; ++j) {
    const float rev = (float)(j * kap) * (1.0f / 2048.0f);
    const float sn = hsin(rev), cs = hcos(rev);
    float t = ur[j] * cs - ui[j] * sn;
    ui[j] = ui[j] * cs + ur[j] * sn;
    ur[j] = t;
  }
  #pragma unroll
  for (int s = 0; s < 6; ++s) {
    const int h = 1 << s;
    const int j = lane & (h - 1);
    const float rev = (float)j * (0.5f / (float)h);
    const bool hi = (lane & h) != 0;
    const float c  = hi ? hcos(rev) : 1.0f;
    const float sv = hi ? hsin(rev) : 0.0f;
    const float sgn = hi ? -1.0f : 1.0f;
    #pragma unroll
    for (int r = 0; r < 32; ++r) {
      float vr = fmaf(-ui[r], sv, ur[r] * c);
      float vi = fmaf(ur[r], sv, ui[r] * c);
      float pvr = __shfl_xor(vr, h, 64);
      float pvi = __shfl_xor(vi, h, 64);
      ur[r] = fmaf(sgn, vr, pvr);
      ui[r] = fmaf(sgn, vi, pvi);
    }
  }
}

// ---------- gate transpose + Hermitian extend + pack (fallback path) ----------
__global__ __launch_bounds__(256) void gate_pack_k(const float* __restrict__ gr,
                                                   const float* __restrict__ gi,
                                                   unsigned int* __restrict__ gt) {
  __shared__ float tr[32][33];
  __shared__ float ti[32][33];
  const int t = threadIdx.x;
  const int k0 = blockIdx.x * 32, hb = blockIdx.y * 32;
  const int hx = t & 31, fr = t >> 5;
  #pragma unroll
  for (int p = 0; p < 4; ++p) {
    int ff = p * 8 + fr;
    int k = k0 + ff;
    int f = (k <= 1024) ? k : (2048 - k);
    float sg = (k <= 1024) ? 1.f : -1.f;
    tr[ff][hx] = gr[(size_t)f * 2048 + hb + hx] * (1.f / 2048.f);
    ti[ff][hx] = sg * gi[(size_t)f * 2048 + hb + hx] * (1.f / 2048.f);
  }
  __syncthreads();
  const int kk = t & 31, hr = t >> 5;
  #pragma unroll
  for (int p = 0; p < 4; ++p) {
    int hl = p * 8 + hr;
    float re = tr[kk][hl], im = ti[kk][hl];
    gt[(size_t)(hb + hl) * 2048 + k0 + kk] =
        (unsigned int)f2bf(re) | ((unsigned int)f2bf(im) << 16);
  }
}

// ---------- A/B table for the rfft path (R12-verified) ----------
__global__ __launch_bounds__(256) void gate_ab_k(const float* __restrict__ gr,
                                                 const float* __restrict__ gi,
                                                 uint2* __restrict__ ab) {
  __shared__ unsigned int uA[32][33];
  __shared__ unsigned int uB[32][33];
  const int t = threadIdx.x;
  const int k0 = blockIdx.x * 32, h0 = blockIdx.y * 32;
  const int c = t & 31, r = t >> 5;
  #pragma unroll
  for (int pp = 0; pp < 4; ++pp) {
    const int kk = pp * 8 + r;
    const int k = k0 + kk;
    const int h = h0 + c;
    const float gkr = gr[(size_t)k * 2048 + h];
    const float gki = gi[(size_t)k * 2048 + h];
    const float gcr = gr[(size_t)(1024 - k) * 2048 + h];
    const float gci = gi[(size_t)(1024 - k) * 2048 + h];
    const float inv = 1.0f / 1024.0f;
    float Ar, Ai, Br, Bi;
    if (k == 0) {
      Ar = (gkr + gcr) * 0.5f * inv; Ai = 0.f;
      Br = 0.f; Bi = (gkr - gcr) * 0.5f * inv;
    } else {
      const float rev = (float)k * (1.0f / 2048.0f);
      const float sn = hsin(rev), cs = hcos(rev);
      const float Sr = (gkr + gcr) * 0.5f, Si = (gki - gci) * 0.5f;
      const float Dr = (gkr - gcr) * 0.5f, Di = (gki + gci) * 0.5f;
      Ar = (Sr - sn * Dr) * inv; Ai = (Si - sn * Di) * inv;
      Br = (-cs * Di) * inv;     Bi = (cs * Dr) * inv;
    }
    uA[kk][c] = pack2bf(Ar, Ai);
    uB[kk][c] = pack2bf(Br, Bi);
  }
  __syncthreads();
  #pragma unroll
  for (int pp = 0; pp < 4; ++pp) {
    const int hh = pp * 8 + r;
    ab[(size_t)(h0 + hh) * 1024 + k0 + c] = make_uint2(uA[c][hh], uB[c][hh]);
  }
}

// ---------- W f32 -> bf16 ----------
__global__ __launch_bounds__(256) void wconv_k(const float* __restrict__ W,
                                               unsigned short* __restrict__ Wb) {
  int i = blockIdx.x * 256 + threadIdx.x;
  float4 v = ((const float4*)W)[i];
  ushort4 o;
  o.x = f2bf(v.x); o.y = f2bf(v.y); o.z = f2bf(v.z); o.w = f2bf(v.w);
  ((ushort4*)Wb)[i] = o;
}

// ---------- T1: x [b,s,h] f32 -> xT [b,h,s] BF16, 64x64 tiles (R15-verified) ----------
__global__ __launch_bounds__(256) void xtrans_k(const float* __restrict__ x,
                                                unsigned short* __restrict__ xT) {
  __shared__ float t[64][65];
  const int b = blockIdx.z;
  const int s0 = blockIdx.x * 64, h0 = blockIdx.y * 64;
  const float* xb = x + ((size_t)b * 2048) * 2048;
  unsigned short* xTb = xT + ((size_t)b * 2048) * 2048;
  const int c4 = (threadIdx.x & 15) * 4;
  const int r0 = threadIdx.x >> 4;
  #pragma unroll
  for (int p = 0; p < 4; ++p) {
    const int rr = p * 16 + r0;
    float4 v = *(const float4*)(xb + (size_t)(s0 + rr) * 2048 + h0 + c4);
    t[rr][c4 + 0] = v.x; t[rr][c4 + 1] = v.y;
    t[rr][c4 + 2] = v.z; t[rr][c4 + 3] = v.w;
  }
  __syncthreads();
  const int j = threadIdx.x & 7;
  const int hr0 = threadIdx.x >> 3;
  #pragma unroll
  for (int p = 0; p < 2; ++p) {
    const int hh = p * 32 + hr0;
    uint4 o;
    o.x = pack2bf(t[j * 8 + 0][hh], t[j * 8 + 1][hh]);
    o.y = pack2bf(t[j * 8 + 2][hh], t[j * 8 + 3][hh]);
    o.z = pack2bf(t[j * 8 + 4][hh], t[j * 8 + 5][hh]);
    o.w = pack2bf(t[j * 8 + 6][hh], t[j * 8 + 7][hh]);
    *(uint4*)(xTb + (size_t)(h0 + hh) * 2048 + s0 + j * 8) = o;
  }
}

// ---------- T2: yT [b,h,s] -> y [b,s,h], bf16 64x64 tiles ----------
__global__ __launch_bounds__(256) void ytrans_k(const unsigned short* __restrict__ yT,
                                                unsigned short* __restrict__ y) {
  __shared__ unsigned short t[64][66];
  const int b = blockIdx.z;
  const int h0 = blockIdx.x * 64, s0 = blockIdx.y * 64;
  const unsigned short* src = yT + ((size_t)b * 2048 + h0) * 2048 + s0;
  unsigned short* dst = y + ((size_t)b * 2048 + s0) * 2048 + h0;
  const int c = threadIdx.x & 15, r = threadIdx.x >> 4;
  #pragma unroll
  for (int p = 0; p < 4; ++p) {
    int rr = p * 16 + r;
    ushort4 v = *(const ushort4*)(src + (size_t)rr * 2048 + c * 4);
    *(ushort4*)&t[rr][c * 4] = v;
  }
  __syncthreads();
  #pragma unroll
  for (int p = 0; p < 4; ++p) {
    int rr = p * 16 + r;
    ushort4 o;
    o.x = t[c * 4 + 0][rr]; o.y = t[c * 4 + 1][rr];
    o.z = t[c * 4 + 2][rr]; o.w = t[c * 4 + 3][rr];
    *(ushort4*)(dst + (size_t)rr * 2048 + c * 4) = o;
  }
}

// ---------- rfft FFT (R15-verified: bf16 input, LDS-staged ab table) ----------
__global__ __attribute__((amdgpu_flat_work_group_size(256, 256)))
__attribute__((amdgpu_waves_per_eu(2, 4)))
void fftr_k(const unsigned short* __restrict__ xT,
            const uint2* __restrict__ ab,
            unsigned short* __restrict__ yT) {
  __shared__ float snap[4][32];
  __shared__ uint2 labs[4][1024];
  const int tid = threadIdx.x;
  const int w = tid >> 6, lane = tid & 63;
  const size_t col = (size_t)blockIdx.x * 4 + w;
  const int h = (int)(col & 2047);
  const int kap = bitrev6(lane);
  constexpr int BR4[16]   = {0,8,4,12,2,10,6,14,1,9,5,13,3,11,7,15};
  constexpr int P0L16[16] = {0,1,3,2,7,6,5,4,15,14,13,12,11,10,9,8};

  {
    const char* gsrc = (const char*)(ab + (size_t)h * 1024);
    char* ldst = (char*)&labs[w][0];
    #pragma unroll
    for (int p8 = 0; p8 < 8; ++p8)
      glds16(gsrc + p8 * 1024 + lane * 16, ldst + p8 * 1024);
  }

  float ur[16], ui[16];
  {
    const unsigned short* xc = xT + col * 2048;
    #pragma unroll
    for (int q = 0; q < 4; ++q) {
      uint4 v = *(const uint4*)(xc + lane * 32 + q * 8);
      ur[4 * q + 0] = bflo(v.x); ui[4 * q + 0] = bfhi(v.x);
      ur[4 * q + 1] = bflo(v.y); ui[4 * q + 1] = bfhi(v.y);
      ur[4 * q + 2] = bflo(v.z); ui[4 * q + 2] = bfhi(v.z);
      ur[4 * q + 3] = bflo(v.w); ui[4 * q + 3] = bfhi(v.w);
    }
  }

  #pragma unroll
  for (int s = 0; s < 6; ++s) {
    const int hh = 32 >> s;
    const int j = lane & (hh - 1);
    const float rev = (float)j * (0.5f / (float)hh);
    const bool hi = (lane & hh) != 0;
    const float c  = hi ? hcos(rev) : 1.0f;
    const float sv = hi ? hsin(rev) : 0.0f;
    const float sgn = hi ? -1.0f : 1.0f;
    #pragma unroll
    for (int r = 0; r < 16; ++r) {
      float pr = __shfl_xor(ur[r], hh, 64);
      float pi = __shfl_xor(ui[r], hh, 64);
      float tr = fmaf(sgn, ur[r], pr);
      float ti = fmaf(sgn, ui[r], pi);
      ur[r] = fmaf(ti, sv, tr * c);
      ui[r] = fmaf(-tr, sv, ti * c);
    }
  }
  #pragma unroll
  for (int j = 1; j < 16; ++j) {
    const float rev = (float)(j * kap) * (1.0f / 1024.0f);
    const float sn = hsin(rev), cs = hcos(rev);
    float t = ur[j] * cs + ui[j] * sn;
    ui[j] = ui[j] * cs - ur[j] * sn;
    ur[j] = t;
  }
  #pragma unroll
  for (int s = 0; s < 4; ++s) {
    const int hh = 8 >> s;
    #pragma unroll
    for (int i = 0; i < 16; ++i) if (!(i & hh)) {
      const int tw = (i & (hh - 1)) * (16 / hh);
      float dr = ur[i] - ur[i + hh], di = ui[i] - ui[i + hh];
      ur[i] += ur[i + hh]; ui[i] += ui[i + hh];
      ur[i + hh] = dr * CW16[tw] + di * SW16[tw];
      ui[i + hh] = di * CW16[tw] - dr * SW16[tw];
    }
  }

  if (lane == 0) {
    #pragma unroll
    for (int p = 0; p < 16; ++p) { snap[w][2 * p] = ur[p]; snap[w][2 * p + 1] = ui[p]; }
  }
  asm volatile("s_waitcnt vmcnt(0)" ::: "memory");
  const int lsrc = bitrev6((64 - kap) & 63);
  const bool l0 = (lane == 0);
  #pragma unroll
  for (int c2 = 0; c2 < 4; ++c2) {
    __builtin_amdgcn_sched_barrier(0);
    #pragma unroll
    for (int pp = 0; pp < 2; ++pp) {
      const int p = c2 * 2 + pp;
      const int pb = 15 - p;
      float arp = __shfl(ur[pb], lsrc), aip = __shfl(ui[pb], lsrc);
      float arq = __shfl(ur[p], lsrc),  aiq = __shfl(ui[p], lsrc);
      float s0r = snap[w][2 * P0L16[p]],  s0i = snap[w][2 * P0L16[p] + 1];
      float s1r = snap[w][2 * P0L16[pb]], s1i = snap[w][2 * P0L16[pb] + 1];
      arp = l0 ? s0r : arp;  aip = l0 ? s0i : aip;
      arq = l0 ? s1r : arq;  aiq = l0 ? s1i : aiq;
      uint2 gp = labs[w][(BR4[p]  << 6) + kap];
      uint2 gq = labs[w][(BR4[pb] << 6) + kap];
      {
        float Ar = bflo(gp.x), Ai = bfhi(gp.x), Br = bflo(gp.y), Bi = bfhi(gp.y);
        float zr = ur[p], zi = ui[p];
        ur[p] = Ar * zr - Ai * zi + Br * arp + Bi * aip;
        ui[p] = Ar * zi + Ai * zr + Bi * arp - Br * aip;
      }
      {
        float Ar = bflo(gq.x), Ai = bfhi(gq.x), Br = bflo(gq.y), Bi = bfhi(gq.y);
        float zr = ur[pb], zi = ui[pb];
        ur[pb] = Ar * zr - Ai * zi + Br * arq + Bi * aiq;
        ui[pb] = Ar * zi + Ai * zr + Bi * arq - Br * aiq;
      }
    }
  }
  __builtin_amdgcn_sched_barrier(0);

  #pragma unroll
  for (int s = 0; s < 4; ++s) {
    const int hh = 1 << s;
    #pragma unroll
    for (int i = 0; i < 16; ++i) if (!(i & hh)) {
      const int tw = (i & (hh - 1)) * (16 / hh);
      float tr2 = ur[i + hh] * CW16[tw] - ui[i + hh] * SW16[tw];
      float ti2 = ui[i + hh] * CW16[tw] + ur[i + hh] * SW16[tw];
      ur[i + hh] = ur[i] - tr2; ui[i + hh] = ui[i] - ti2;
      ur[i] += tr2; ui[i] += ti2;
    }
  }
  #pragma unroll
  for (int j = 1; j < 16; ++j) {
    const float rev = (float)(j * kap) * (1.0f / 1024.0f);
    const float sn = hsin(rev), cs = hcos(rev);
    float t = ur[j] * cs - ui[j] * sn;
    ui[j] = ui[j] * cs + ur[j] * sn;
    ur[j] = t;
  }
  #pragma unroll
  for (int s = 0; s < 6; ++s) {
    const int hh = 1 << s;
    const int j = lane & (hh - 1);
    const float rev = (float)j * (0.5f / (float)hh);
    const bool hi = (lane & hh) != 0;
    const float c  = hi ? hcos(rev) : 1.0f;
    const float sv = hi ? hsin(rev) : 0.0f;
    const float sgn = hi ? -1.0f : 1.0f;
    #pragma unroll
    for (int r = 0; r < 16; ++r) {
      float vr = fmaf(-ui[r], sv, ur[r] * c);
      float vi = fmaf(ur[r], sv, ui[r] * c);
      float pvr = __shfl_xor(vr, hh, 64);
      float pvi = __shfl_xor(vi, hh, 64);
      ur[r] = fmaf(sgn, vr, pvr);
      ui[r] = fmaf(sgn, vi, pvi);
    }
  }

  uint4* dst = (uint4*)(yT + col * 2048) + lane * 4;
  #pragma unroll
  for (int g = 0; g < 4; ++g) {
    uint4 o;
    o.x = pack2bf(ur[4 * g + 0], ui[4 * g + 0]);
    o.y = pack2bf(ur[4 * g + 1], ui[4 * g + 1]);
    o.z = pack2bf(ur[4 * g + 2], ui[4 * g + 2]);
    o.w = pack2bf(ur[4 * g + 3], ui[4 * g + 3]);
    dst[g] = o;
  }
}

// ---------- fallback (R3-proven): FFT-2048 reading x directly via LDS staging ----------
__global__ __attribute__((amdgpu_flat_work_group_size(512, 512)))
__attribute__((amdgpu_waves_per_eu(2, 4)))
void fft_gate_k(const float* __restrict__ x,
                const unsigned int* __restrict__ gt,
                unsigned short* __restrict__ y) {
  __shared__ float lds[8 * 516];
  const int tid = threadIdx.x;
  const int w = tid >> 6;
  const int lane = tid & 63;
  const int bid = blockIdx.x;
  const int swz = (bid & 7) * 256 + (bid >> 3);
  const int h0 = (swz & 255) << 3;
  const int b = swz >> 8;
  const int hh = tid & 7, srow = tid >> 3;

  float ur[32], ui[32];
  const size_t xbase = ((size_t)b * 2048) * 2048 + h0;

  for (int c = 0; c < 4; ++c) {
    #pragma unroll
    for (int q = 0; q < 8; ++q) {
      int soff = q * 64 + srow;
      float v = x[xbase + (size_t)(c * 512 + soff) * 2048 + hh];
      lds[hh * 516 + (soff ^ ((soff >> 5) & 15))] = v;
    }
    __syncthreads();
    if ((lane >> 4) == c) {
      const int li = lane & 15;
      #pragma unroll
      for (int j = 0; j < 32; ++j) {
        ur[j] = lds[w * 516 + ((32 * li + j) ^ li)];
        ui[j] = 0.f;
      }
    }
    __syncthreads();
  }

  fwd_core(ur, ui, lane);
  {
    const int kap = bitrev6(lane);
    const unsigned int* grow = gt + (size_t)(h0 + w) * 2048;
    #pragma unroll
    for (int p = 0; p < 32; ++p) {
      unsigned int g = grow[(BR5[p] << 6) + kap];
      float gre = bflo(g), gim = bfhi(g);
      float t = ur[p] * gre - ui[p] * gim;
      ui[p] = ur[p] * gim + ui[p] * gre;
      ur[p] = t;
    }
  }
  inv_core(ur, ui, lane);

  for (int c = 0; c < 4; ++c) {
    if ((lane >> 4) == c) {
      const int li = lane & 15;
      #pragma unroll
      for (int r = 0; r < 32; ++r)
        lds[w * 516 + ((32 * li + r) ^ li)] = ur[r];
    }
    __syncthreads();
    #pragma unroll
    for (int q = 0; q < 8; ++q) {
      int soff = q * 64 + srow;
      float v = lds[hh * 516 + (soff ^ ((soff >> 5) & 15))];
      y[xbase + (size_t)(c * 512 + soff) * 2048 + hh] = f2bf(v);
    }
    __syncthreads();
  }
}

// ---------- GEMM fallback: m97-style 128x128 tile ----------
__global__ __launch_bounds__(256) void gemm_k(const unsigned short* __restrict__ A,
                                              const unsigned short* __restrict__ Bw,
                                              const float* __restrict__ bias,
                                              float* __restrict__ C) {
  __shared__ unsigned short sA[128 * 32];
  __shared__ unsigned short sB[128 * 32];
  const int tid = threadIdx.x;
  const int nwg = gridDim.x;
  const int cpx = nwg >> 3;
  const int bid = blockIdx.x;
  const int swz = (bid & 7) * cpx + (bid >> 3);
  const int bm = swz >> 4, bn = swz & 15;
  const int m0 = bm << 7, n0 = bn << 7;
  const int w = tid >> 6, lane = tid & 63;
  const int arow = tid >> 2, koff = (tid & 3) << 3;
  const unsigned short* gA = A + (size_t)(m0 + arow) * 2048 + koff;
  const unsigned short* gB = Bw + (size_t)(n0 + arow) * 2048 + koff;
  char* sAb = (char*)sA + w * 1024;
  char* sBb = (char*)sB + w * 1024;

  f32x4 acc[4][4];
  #pragma unroll
  for (int i = 0; i < 4; ++i)
    #pragma unroll
    for (int j = 0; j < 4; ++j) acc[i][j] = (f32x4){0.f, 0.f, 0.f, 0.f};

  const int wr = w >> 1, wc = w & 1;
  const int row16 = lane & 15, kb = lane >> 4;

  for (int k0 = 0; k0 < 2048; k0 += 32) {
    glds16(gA + k0, sAb);
    glds16(gA + 64 * 2048 + k0, sAb + 4096);
    glds16(gB + k0, sBb);
    glds16(gB + 64 * 2048 + k0, sBb + 4096);
    __syncthreads();
    bf16x8 af[4], bfr[4];
    #pragma unroll
    for (int i = 0; i < 4; ++i) {
      int r = (wr << 6) + (i << 4) + row16;
      af[i] = *(const bf16x8*)(sA + r * 32 + (kb << 3));
    }
    #pragma unroll
    for (int j2 = 0; j2 < 4; ++j2) {
      int r = (wc << 6) + (j2 << 4) + row16;
      bfr[j2] = *(const bf16x8*)(sB + r * 32 + (kb << 3));
    }
    #pragma unroll
    for (int i = 0; i < 4; ++i)
      #pragma unroll
      for (int j2 = 0; j2 < 4; ++j2)
        acc[i][j2] = __builtin_amdgcn_mfma_f32_16x16x32_bf16(af[i], bfr[j2], acc[i][j2], 0, 0, 0);
    __syncthreads();
  }

  const int rq = lane >> 4;
  #pragma unroll
  for (int j2 = 0; j2 < 4; ++j2) {
    int oc = n0 + (wc << 6) + (j2 << 4) + row16;
    float bj = bias[oc];
    #pragma unroll
    for (int i = 0; i < 4; ++i) {
      int mr = m0 + (wr << 6) + (i << 4) + (rq << 2);
      #pragma unroll
      for (int q = 0; q < 4; ++q)
        C[(size_t)(mr + q) * 2048 + oc] = acc[i][j2][q] + bj;
    }
  }
}

// ---------- GEMM main: 128x256 tile, 4 waves, 3-stage pipeline, 2 blocks/CU ----------
// R15 counters: gemm8 at 41% MfmaUtil with 1 block/CU — during every
// ds_read/barrier region the MFMA pipe idles with no co-resident block to fill
// it (m114: cross-wave MFMA/VALU co-schedule ≈ max not sum). This kernel: 256
// threads (4 waves, 1M x 4N), 3 x 24KB LDS buffers = 72KB -> 2 blocks/CU; the
// verified R13 2-phase K-step schedule; counted vmcnt(6) (stage t+2 ~= 1060cy
// ahead > 900cy HBM). Invariants: STAGE(t+2) -> buffer (t+2)%3 = (t-1)%3 whose
// last reads ended at iter t-1's ph2 barrier; end-of-iter vmcnt(6) leaves the
// 6 loads of t+2 in flight = tile t+1 landed.
__global__ __launch_bounds__(256) void gemm4_k(const unsigned short* __restrict__ A,
                                               const unsigned short* __restrict__ Bw,
                                               const float* __restrict__ bias,
                                               float* __restrict__ C) {
  extern __shared__ char lds[];   // 3 x (A 8KB + B 16KB) = 72KB
  const int tid = threadIdx.x;
  const int w = tid >> 6, lane = tid & 63;
  const int bid = blockIdx.x;
  const int swz = (bid & 7) * 128 + (bid >> 3);  // 1024 wgs, 8 XCDs, bijective
  const int m0 = (swz >> 3) << 7;                // 128 m-tiles
  const int n0 = (swz & 7) << 8;                 // 8 n-tiles (256 wide)
  const int wc = w;                              // 4 waves over N
  const int row16 = lane & 15, kb = lane >> 4;

  // staging: per glds16 sweep a wave covers rows [c*64 + w*16 + lane/4), seg lane&3
  const int rs = (w << 4) + (lane >> 2);         // 0..63
  const int sseg = (lane & 3) ^ ((rs >> 1) & 3); // swizzled k-segment (c*64 keeps bits1-2)
  const unsigned short* pA = A  + (size_t)(m0 + rs) * 2048 + (sseg << 3);
  const unsigned short* pB = Bw + (size_t)(n0 + rs) * 2048 + (sseg << 3);
  const int dW = w << 10;                        // wave's 1KB slice within a sweep

  f32x4 acc[8][4];
  #pragma unroll
  for (int i = 0; i < 8; ++i)
    #pragma unroll
    for (int j = 0; j < 4; ++j) acc[i][j] = (f32x4){0.f, 0.f, 0.f, 0.f};

  auto STAGE = [&](int t) {                      // 6 glds16: A 2 sweeps, B 4 sweeps
    char* base = lds + (t % 3) * 24576;
    const int k0 = t << 5;
    glds16(pA + k0, base + dW);                          // A rows   0..63
    glds16(pA + 64 * 2048 + k0, base + 4096 + dW);       // A rows  64..127
    glds16(pB + k0, base + 8192 + dW);                   // B rows   0..63
    glds16(pB + 64 * 2048 + k0, base + 12288 + dW);      // B rows  64..127
    glds16(pB + 128 * 2048 + k0, base + 16384 + dW);     // B rows 128..191
    glds16(pB + 192 * 2048 + k0, base + 20480 + dW);     // B rows 192..255
  };
  auto LDA4 = [&](const char* base, int i0, bf16x8 (&af)[4]) {
    #pragma unroll
    for (int i = 0; i < 4; ++i) {
      const int r = ((i0 + i) << 4) + row16;
      af[i] = *(const bf16x8*)(base + (r << 6) + ((kb ^ ((r >> 1) & 3)) << 4));
    }
  };
  auto LDB4 = [&](const char* base, bf16x8 (&bfr)[4]) {
    #pragma unroll
    for (int j = 0; j < 4; ++j) {
      const int r = (wc << 6) + (j << 4) + row16;
      bfr[j] = *(const bf16x8*)(base + 8192 + (r << 6) + ((kb ^ ((r >> 1) & 3)) << 4));
    }
  };
  auto MM16 = [&](const bf16x8 (&af)[4], const bf16x8 (&bfr)[4], int i0) {
    #pragma unroll
    for (int i = 0; i < 4; ++i)
      #pragma unroll
      for (int j = 0; j < 4; ++j)
        acc[i0 + i][j] = __builtin_amdgcn_mfma_f32_16x16x32_bf16(af[i], bfr[j], acc[i0 + i][j], 0, 0, 0);
  };

  // prologue: stage tiles 0,1; wait tile 0 (6 loads of tile 1 in flight)
  STAGE(0); STAGE(1);
  asm volatile("s_waitcnt vmcnt(6)" ::: "memory");
  __builtin_amdgcn_s_barrier();
  __builtin_amdgcn_sched_barrier(0);

  for (int t = 0; t < 62; ++t) {
    const char* base = lds + (t % 3) * 24576;
    // ---- phase 1 ----
    bf16x8 af[4], bfr[4];
    LDA4(base, 0, af);
    LDB4(base, bfr);
    STAGE(t + 2);
    asm volatile("s_waitcnt lgkmcnt(0)" ::: "memory");
    __builtin_amdgcn_sched_barrier(0);      // rule #18
    __builtin_amdgcn_s_setprio(1);
    MM16(af, bfr, 0);
    __builtin_amdgcn_s_setprio(0);
    __builtin_amdgcn_s_barrier();
    // ---- phase 2 ----
    bf16x8 af2[4];
    LDA4(base, 4, af2);
    asm volatile("s_waitcnt lgkmcnt(0)" ::: "memory");
    __builtin_amdgcn_sched_barrier(0);
    __builtin_amdgcn_s_setprio(1);
    MM16(af2, bfr, 4);
    __builtin_amdgcn_s_setprio(0);
    asm volatile("s_waitcnt vmcnt(6)" ::: "memory");   // tile t+1 landed
    __builtin_amdgcn_s_barrier();
    __builtin_amdgcn_sched_barrier(0);
  }
  // t = 62: no stage; drain tile 63
  {
    const char* base = lds + (62 % 3) * 24576;
    bf16x8 af[4], af2[4], bfr[4];
    LDA4(base, 0, af); LDA4(base, 4, af2); LDB4(base, bfr);
    MM16(af, bfr, 0); MM16(af2, bfr, 4);
    asm volatile("s_waitcnt vmcnt(0)" ::: "memory");
    __builtin_amdgcn_s_barrier();
    __builtin_amdgcn_sched_barrier(0);
  }
  // t = 63
  {
    const char* base = lds + (63 % 3) * 24576;
    bf16x8 af[4], af2[4], bfr[4];
    LDA4(base, 0, af); LDA4(base, 4, af2); LDB4(base, bfr);
    MM16(af, bfr, 0); MM16(af2, bfr, 4);
  }

  // epilogue
  const int rq = lane >> 4;
  #pragma unroll
  for (int j = 0; j < 4; ++j) {
    const int oc = n0 + (wc << 6) + (j << 4) + row16;
    const float bj = bias[oc];
    #pragma unroll
    for (int i = 0; i < 8; ++i) {
      const int mr = m0 + (i << 4) + (rq << 2);
      #pragma unroll
      for (int q = 0; q < 4; ++q)
        C[(size_t)(mr + q) * 2048 + oc] = acc[i][j][q] + bj;
    }
  }
}

extern "C" void kernel_launch(void* const* d_in, const int* in_sizes, int n_in,
                              void* d_out, int out_size, void* d_ws, size_t ws_size,
                              hipStream_t stream) {
  const float* x  = (const float*)d_in[0];
  const float* gr = (const float*)d_in[1];
  const float* gi = (const float*)d_in[2];
  const float* W  = (const float*)d_in[3];
  const float* bs = (const float*)d_in[4];
  float* out = (float*)d_out;

  char* ws = (char*)d_ws;
  unsigned short* yb = (unsigned short*)ws;                          // 64 MB  y bf16 [b,s,h]
  unsigned short* Wb = (unsigned short*)(ws + (64ull << 20));        // 8 MB   W bf16
  unsigned int*   gt = (unsigned int*)(ws + (72ull << 20));          // 16 MB  gate (fallback)
  uint2*          ab = (uint2*)(ws + (72ull << 20));                 // 16 MB  A/B table (fast)
  unsigned short* xT = (unsigned short*)(ws + (88ull << 20));        // 64 MB  x transposed BF16 [b,h,s]
  unsigned short* yT = (unsigned short*)(ws + (216ull << 20));       // 64 MB  y transposed [b,h,s]
  const bool fast = ws_size >= (280ull << 20);

  hipLaunchKernelGGL(wconv_k, dim3(4096), dim3(256), 0, stream, W, Wb);
  if (fast) {
    hipLaunchKernelGGL(gate_ab_k, dim3(32, 64), dim3(256), 0, stream, gr, gi, ab);
    hipLaunchKernelGGL(xtrans_k, dim3(32, 32, 8), dim3(256), 0, stream, x, xT);
    hipLaunchKernelGGL(fftr_k, dim3(4096), dim3(256), 0, stream, xT, ab, yT);
    hipLaunchKernelGGL(ytrans_k, dim3(32, 32, 8), dim3(256), 0, stream, yT, yb);
  } else {
    hipLaunchKernelGGL(gate_pack_k, dim3(64, 64), dim3(256), 0, stream, gr, gi, gt);
    hipLaunchKernelGGL(fft_gate_k, dim3(2048), dim3(512), 0, stream, x, gt, yb);
  }

  // 72 KiB dynamic LDS (above the 64 KiB default cap)
  const bool big = hipFuncSetAttribute((const void*)gemm4_k,
                                       hipFuncAttributeMaxDynamicSharedMemorySize,
                                       73728) == hipSuccess;
  if (big) {
    hipLaunchKernelGGL(gemm4_k, dim3(1024), dim3(256), 73728, stream, yb, Wb, bs, out);
  } else {
    hipLaunchKernelGGL(gemm_k, dim3(2048), dim3(256), 0, stream, yb, Wb, bs, out);
  }
}

// Round 18
// 336.462 us; speedup vs baseline: 1.2029x; 1.2029x over previous
//
#include <hip/hip_runtime.h>
#include <math.h>

typedef __attribute__((ext_vector_type(8))) short bf16x8;
typedef __attribute__((ext_vector_type(4))) float f32x4;

__device__ __forceinline__ unsigned short f2bf(float f) {
  unsigned int u = __float_as_uint(f);
  unsigned int r = (u + 0x7fffu + ((u >> 16) & 1u)) >> 16;
  return (unsigned short)r;
}
__device__ __forceinline__ unsigned int pack2bf(float a, float b) {
  return (unsigned int)f2bf(a) | ((unsigned int)f2bf(b) << 16);
}
__device__ __forceinline__ float bflo(unsigned int g) { return __uint_as_float(g << 16); }
__device__ __forceinline__ float bfhi(unsigned int g) { return __uint_as_float(g & 0xffff0000u); }

__device__ __forceinline__ void glds16(const void* gp, void* lp) {
  __builtin_amdgcn_global_load_lds(
      (const __attribute__((address_space(1))) void*)gp,
      (__attribute__((address_space(3))) void*)lp, 16, 0, 0);
}

// cos/sin(pi*j/16), j=0..15 — cover all in-lane FFT16/FFT32 twiddles
__device__ __constant__ float CW16[16] = {
  1.0f, 0.9807852804032304f, 0.9238795325112867f, 0.8314696123025452f,
  0.7071067811865476f, 0.5555702330196022f, 0.3826834323650898f, 0.19509032201612828f,
  0.0f, -0.19509032201612828f, -0.3826834323650898f, -0.5555702330196022f,
  -0.7071067811865476f, -0.8314696123025452f, -0.9238795325112867f, -0.9807852804032304f};
__device__ __constant__ float SW16[16] = {
  0.0f, 0.19509032201612828f, 0.3826834323650898f, 0.5555702330196022f,
  0.7071067811865476f, 0.8314696123025452f, 0.9238795325112867f, 0.9807852804032304f,
  1.0f, 0.9807852804032304f, 0.9238795325112867f, 0.8314696123025452f,
  0.7071067811865476f, 0.5555702330196022f, 0.3826834323650898f, 0.19509032201612828f};
__device__ __constant__ int BR5[32] = {
  0,16,8,24,4,20,12,28,2,18,10,26,6,22,14,30,
  1,17,9,25,5,21,13,29,3,19,11,27,7,23,15,31};

__device__ __forceinline__ int bitrev6(int l) {
  return ((l&1)<<5)|((l&2)<<3)|((l&4)<<1)|((l&8)>>1)|((l&16)>>3)|((l&32)>>5);
}

// hardware sin/cos: input in REVOLUTIONS (angle/2pi); all our args are in [0,1)
__device__ __forceinline__ float hsin(float rev) { return __builtin_amdgcn_sinf(rev); }
__device__ __forceinline__ float hcos(float rev) { return __builtin_amdgcn_cosf(rev); }

// ================= 2048-point cores (fallback path only) =================
__device__ __forceinline__ void fwd_core(float (&ur)[32], float (&ui)[32], const int lane) {
  #pragma unroll
  for (int s = 0; s < 6; ++s) {
    const int h = 32 >> s;
    const int j = lane & (h - 1);
    const float rev = (float)j * (0.5f / (float)h);
    const bool hi = (lane & h) != 0;
    const float c  = hi ? hcos(rev) : 1.0f;
    const float sv = hi ? hsin(rev) : 0.0f;
    const float sgn = hi ? -1.0f : 1.0f;
    #pragma unroll
    for (int r = 0; r < 32; ++r) {
      float pr = __shfl_xor(ur[r], h, 64);
      float pi = __shfl_xor(ui[r], h, 64);
      float tr = fmaf(sgn, ur[r], pr);
      float ti = fmaf(sgn, ui[r], pi);
      ur[r] = fmaf(ti, sv, tr * c);
      ui[r] = fmaf(-tr, sv, ti * c);
    }
  }
  const int kap = bitrev6(lane);
  #pragma unroll
  for (int j = 1; j < 32; ++j) {
    const float rev = (float)(j * kap) * (1.0f / 2048.0f);
    const float sn = hsin(rev), cs = hcos(rev);
    float t = ur[j] * cs + ui[j] * sn;
    ui[j] = ui[j] * cs - ur[j] * sn;
    ur[j] = t;
  }
  #pragma unroll
  for (int s = 0; s < 5; ++s) {
    const int h = 16 >> s;
    #pragma unroll
    for (int i = 0; i < 32; ++i) if (!(i & h)) {
      const int tw = (i & (h - 1)) * (16 / h);
      float dr = ur[i] - ur[i + h], di = ui[i] - ui[i + h];
      ur[i] += ur[i + h]; ui[i] += ui[i + h];
      ur[i + h] = dr * CW16[tw] + di * SW16[tw];
      ui[i + h] = di * CW16[tw] - dr * SW16[tw];
    }
  }
}

__device__ __forceinline__ void inv_core(float (&ur)[32], float (&ui)[32], const int lane) {
  const int kap = bitrev6(lane);
  #pragma unroll
  for (int s = 0; s < 5; ++s) {
    const int h = 1 << s;
    #pragma unroll
    for (int i = 0; i < 32; ++i) if (!(i & h)) {
      const int tw = (i & (h - 1)) * (16 / h);
      float tr2 = ur[i + h] * CW16[tw] - ui[i + h] * SW16[tw];
      float ti2 = ui[i + h] * CW16[tw] + ur[i + h] * SW16[tw];
      ur[i + h] = ur[i] - tr2; ui[i + h] = ui[i] - ti2;
      ur[i] += tr2; ui[i] += ti2;
    }
  }
  #pragma unroll
  for (int j = 1; j < 32; ++j) {
    const float rev = (float)(j * kap) * (1.0f / 2048.0f);
    const float sn = hsin(rev), cs = hcos(rev);
    float t = ur[j] * cs - ui[j] * sn;
    ui[j] = ui[j] * cs + ur[j] * sn;
    ur[j] = t;
  }
  #pragma unroll
  for (int s = 0; s < 6; ++s) {
    const int h = 1 << s;
    const int j = lane & (h - 1);
    const float rev = (float)j * (0.5f / (float)h);
    const bool hi = (lane & h) != 0;
    const float c  = hi ? hcos(rev) : 1.0f;
    const float sv = hi ? hsin(rev) : 0.0f;
    const float sgn = hi ? -1.0f : 1.0f;
    #pragma unroll
    for (int r = 0; r < 32; ++r) {
      float vr = fmaf(-ui[r], sv, ur[r] * c);
      float vi = fmaf(ur[r], sv, ui[r] * c);
      float pvr = __shfl_xor(vr, h, 64);
      float pvi = __shfl_xor(vi, h, 64);
      ur[r] = fmaf(sgn, vr, pvr);
      ui[r] = fmaf(sgn, vi, pvi);
    }
  }
}

// ---------- gate transpose + Hermitian extend + pack (fallback path) ----------
__global__ __launch_bounds__(256) void gate_pack_k(const float* __restrict__ gr,
                                                   const float* __restrict__ gi,
                                                   unsigned int* __restrict__ gt) {
  __shared__ float tr[32][33];
  __shared__ float ti[32][33];
  const int t = threadIdx.x;
  const int k0 = blockIdx.x * 32, hb = blockIdx.y * 32;
  const int hx = t & 31, fr = t >> 5;
  #pragma unroll
  for (int p = 0; p < 4; ++p) {
    int ff = p * 8 + fr;
    int k = k0 + ff;
    int f = (k <= 1024) ? k : (2048 - k);
    float sg = (k <= 1024) ? 1.f : -1.f;
    tr[ff][hx] = gr[(size_t)f * 2048 + hb + hx] * (1.f / 2048.f);
    ti[ff][hx] = sg * gi[(size_t)f * 2048 + hb + hx] * (1.f / 2048.f);
  }
  __syncthreads();
  const int kk = t & 31, hr = t >> 5;
  #pragma unroll
  for (int p = 0; p < 4; ++p) {
    int hl = p * 8 + hr;
    float re = tr[kk][hl], im = ti[kk][hl];
    gt[(size_t)(hb + hl) * 2048 + k0 + kk] =
        (unsigned int)f2bf(re) | ((unsigned int)f2bf(im) << 16);
  }
}

// ---------- A/B table for the rfft path (R12-verified) ----------
__global__ __launch_bounds__(256) void gate_ab_k(const float* __restrict__ gr,
                                                 const float* __restrict__ gi,
                                                 uint2* __restrict__ ab) {
  __shared__ unsigned int uA[32][33];
  __shared__ unsigned int uB[32][33];
  const int t = threadIdx.x;
  const int k0 = blockIdx.x * 32, h0 = blockIdx.y * 32;
  const int c = t & 31, r = t >> 5;
  #pragma unroll
  for (int pp = 0; pp < 4; ++pp) {
    const int kk = pp * 8 + r;
    const int k = k0 + kk;
    const int h = h0 + c;
    const float gkr = gr[(size_t)k * 2048 + h];
    const float gki = gi[(size_t)k * 2048 + h];
    const float gcr = gr[(size_t)(1024 - k) * 2048 + h];
    const float gci = gi[(size_t)(1024 - k) * 2048 + h];
    const float inv = 1.0f / 1024.0f;
    float Ar, Ai, Br, Bi;
    if (k == 0) {
      Ar = (gkr + gcr) * 0.5f * inv; Ai = 0.f;
      Br = 0.f; Bi = (gkr - gcr) * 0.5f * inv;
    } else {
      const float rev = (float)k * (1.0f / 2048.0f);
      const float sn = hsin(rev), cs = hcos(rev);
      const float Sr = (gkr + gcr) * 0.5f, Si = (gki - gci) * 0.5f;
      const float Dr = (gkr - gcr) * 0.5f, Di = (gki + gci) * 0.5f;
      Ar = (Sr - sn * Dr) * inv; Ai = (Si - sn * Di) * inv;
      Br = (-cs * Di) * inv;     Bi = (cs * Dr) * inv;
    }
    uA[kk][c] = pack2bf(Ar, Ai);
    uB[kk][c] = pack2bf(Br, Bi);
  }
  __syncthreads();
  #pragma unroll
  for (int pp = 0; pp < 4; ++pp) {
    const int hh = pp * 8 + r;
    ab[(size_t)(h0 + hh) * 1024 + k0 + c] = make_uint2(uA[c][hh], uB[c][hh]);
  }
}

// ---------- W f32 -> bf16 ----------
__global__ __launch_bounds__(256) void wconv_k(const float* __restrict__ W,
                                               unsigned short* __restrict__ Wb) {
  int i = blockIdx.x * 256 + threadIdx.x;
  float4 v = ((const float4*)W)[i];
  ushort4 o;
  o.x = f2bf(v.x); o.y = f2bf(v.y); o.z = f2bf(v.z); o.w = f2bf(v.w);
  ((ushort4*)Wb)[i] = o;
}

// ---------- T1: x [b,s,h] f32 -> xT [b,h,s] BF16, 64x64 tiles (R15-verified) ----------
__global__ __launch_bounds__(256) void xtrans_k(const float* __restrict__ x,
                                                unsigned short* __restrict__ xT) {
  __shared__ float t[64][65];
  const int b = blockIdx.z;
  const int s0 = blockIdx.x * 64, h0 = blockIdx.y * 64;
  const float* xb = x + ((size_t)b * 2048) * 2048;
  unsigned short* xTb = xT + ((size_t)b * 2048) * 2048;
  const int c4 = (threadIdx.x & 15) * 4;
  const int r0 = threadIdx.x >> 4;
  #pragma unroll
  for (int p = 0; p < 4; ++p) {
    const int rr = p * 16 + r0;
    float4 v = *(const float4*)(xb + (size_t)(s0 + rr) * 2048 + h0 + c4);
    t[rr][c4 + 0] = v.x; t[rr][c4 + 1] = v.y;
    t[rr][c4 + 2] = v.z; t[rr][c4 + 3] = v.w;
  }
  __syncthreads();
  const int j = threadIdx.x & 7;
  const int hr0 = threadIdx.x >> 3;
  #pragma unroll
  for (int p = 0; p < 2; ++p) {
    const int hh = p * 32 + hr0;
    uint4 o;
    o.x = pack2bf(t[j * 8 + 0][hh], t[j * 8 + 1][hh]);
    o.y = pack2bf(t[j * 8 + 2][hh], t[j * 8 + 3][hh]);
    o.z = pack2bf(t[j * 8 + 4][hh], t[j * 8 + 5][hh]);
    o.w = pack2bf(t[j * 8 + 6][hh], t[j * 8 + 7][hh]);
    *(uint4*)(xTb + (size_t)(h0 + hh) * 2048 + s0 + j * 8) = o;
  }
}

// ---------- T2: yT [b,h,s] -> y [b,s,h], bf16 64x64 tiles ----------
__global__ __launch_bounds__(256) void ytrans_k(const unsigned short* __restrict__ yT,
                                                unsigned short* __restrict__ y) {
  __shared__ unsigned short t[64][66];
  const int b = blockIdx.z;
  const int h0 = blockIdx.x * 64, s0 = blockIdx.y * 64;
  const unsigned short* src = yT + ((size_t)b * 2048 + h0) * 2048 + s0;
  unsigned short* dst = y + ((size_t)b * 2048 + s0) * 2048 + h0;
  const int c = threadIdx.x & 15, r = threadIdx.x >> 4;
  #pragma unroll
  for (int p = 0; p < 4; ++p) {
    int rr = p * 16 + r;
    ushort4 v = *(const ushort4*)(src + (size_t)rr * 2048 + c * 4);
    *(ushort4*)&t[rr][c * 4] = v;
  }
  __syncthreads();
  #pragma unroll
  for (int p = 0; p < 4; ++p) {
    int rr = p * 16 + r;
    ushort4 o;
    o.x = t[c * 4 + 0][rr]; o.y = t[c * 4 + 1][rr];
    o.z = t[c * 4 + 2][rr]; o.w = t[c * 4 + 3][rr];
    *(ushort4*)(dst + (size_t)rr * 2048 + c * 4) = o;
  }
}

// ---------- rfft FFT (R15-verified: bf16 input, LDS-staged ab table) ----------
__global__ __attribute__((amdgpu_flat_work_group_size(256, 256)))
__attribute__((amdgpu_waves_per_eu(2, 4)))
void fftr_k(const unsigned short* __restrict__ xT,
            const uint2* __restrict__ ab,
            unsigned short* __restrict__ yT) {
  __shared__ float snap[4][32];
  __shared__ uint2 labs[4][1024];
  const int tid = threadIdx.x;
  const int w = tid >> 6, lane = tid & 63;
  const size_t col = (size_t)blockIdx.x * 4 + w;
  const int h = (int)(col & 2047);
  const int kap = bitrev6(lane);
  constexpr int BR4[16]   = {0,8,4,12,2,10,6,14,1,9,5,13,3,11,7,15};
  constexpr int P0L16[16] = {0,1,3,2,7,6,5,4,15,14,13,12,11,10,9,8};

  {
    const char* gsrc = (const char*)(ab + (size_t)h * 1024);
    char* ldst = (char*)&labs[w][0];
    #pragma unroll
    for (int p8 = 0; p8 < 8; ++p8)
      glds16(gsrc + p8 * 1024 + lane * 16, ldst + p8 * 1024);
  }

  float ur[16], ui[16];
  {
    const unsigned short* xc = xT + col * 2048;
    #pragma unroll
    for (int q = 0; q < 4; ++q) {
      uint4 v = *(const uint4*)(xc + lane * 32 + q * 8);
      ur[4 * q + 0] = bflo(v.x); ui[4 * q + 0] = bfhi(v.x);
      ur[4 * q + 1] = bflo(v.y); ui[4 * q + 1] = bfhi(v.y);
      ur[4 * q + 2] = bflo(v.z); ui[4 * q + 2] = bfhi(v.z);
      ur[4 * q + 3] = bflo(v.w); ui[4 * q + 3] = bfhi(v.w);
    }
  }

  #pragma unroll
  for (int s = 0; s < 6; ++s) {
    const int hh = 32 >> s;
    const int j = lane & (hh - 1);
    const float rev = (float)j * (0.5f / (float)hh);
    const bool hi = (lane & hh) != 0;
    const float c  = hi ? hcos(rev) : 1.0f;
    const float sv = hi ? hsin(rev) : 0.0f;
    const float sgn = hi ? -1.0f : 1.0f;
    #pragma unroll
    for (int r = 0; r < 16; ++r) {
      float pr = __shfl_xor(ur[r], hh, 64);
      float pi = __shfl_xor(ui[r], hh, 64);
      float tr = fmaf(sgn, ur[r], pr);
      float ti = fmaf(sgn, ui[r], pi);
      ur[r] = fmaf(ti, sv, tr * c);
      ui[r] = fmaf(-tr, sv, ti * c);
    }
  }
  #pragma unroll
  for (int j = 1; j < 16; ++j) {
    const float rev = (float)(j * kap) * (1.0f / 1024.0f);
    const float sn = hsin(rev), cs = hcos(rev);
    float t = ur[j] * cs + ui[j] * sn;
    ui[j] = ui[j] * cs - ur[j] * sn;
    ur[j] = t;
  }
  #pragma unroll
  for (int s = 0; s < 4; ++s) {
    const int hh = 8 >> s;
    #pragma unroll
    for (int i = 0; i < 16; ++i) if (!(i & hh)) {
      const int tw = (i & (hh - 1)) * (16 / hh);
      float dr = ur[i] - ur[i + hh], di = ui[i] - ui[i + hh];
      ur[i] += ur[i + hh]; ui[i] += ui[i + hh];
      ur[i + hh] = dr * CW16[tw] + di * SW16[tw];
      ui[i + hh] = di * CW16[tw] - dr * SW16[tw];
    }
  }

  if (lane == 0) {
    #pragma unroll
    for (int p = 0; p < 16; ++p) { snap[w][2 * p] = ur[p]; snap[w][2 * p + 1] = ui[p]; }
  }
  asm volatile("s_waitcnt vmcnt(0)" ::: "memory");
  const int lsrc = bitrev6((64 - kap) & 63);
  const bool l0 = (lane == 0);
  #pragma unroll
  for (int c2 = 0; c2 < 4; ++c2) {
    __builtin_amdgcn_sched_barrier(0);
    #pragma unroll
    for (int pp = 0; pp < 2; ++pp) {
      const int p = c2 * 2 + pp;
      const int pb = 15 - p;
      float arp = __shfl(ur[pb], lsrc), aip = __shfl(ui[pb], lsrc);
      float arq = __shfl(ur[p], lsrc),  aiq = __shfl(ui[p], lsrc);
      float s0r = snap[w][2 * P0L16[p]],  s0i = snap[w][2 * P0L16[p] + 1];
      float s1r = snap[w][2 * P0L16[pb]], s1i = snap[w][2 * P0L16[pb] + 1];
      arp = l0 ? s0r : arp;  aip = l0 ? s0i : aip;
      arq = l0 ? s1r : arq;  aiq = l0 ? s1i : aiq;
      uint2 gp = labs[w][(BR4[p]  << 6) + kap];
      uint2 gq = labs[w][(BR4[pb] << 6) + kap];
      {
        float Ar = bflo(gp.x), Ai = bfhi(gp.x), Br = bflo(gp.y), Bi = bfhi(gp.y);
        float zr = ur[p], zi = ui[p];
        ur[p] = Ar * zr - Ai * zi + Br * arp + Bi * aip;
        ui[p] = Ar * zi + Ai * zr + Bi * arp - Br * aip;
      }
      {
        float Ar = bflo(gq.x), Ai = bfhi(gq.x), Br = bflo(gq.y), Bi = bfhi(gq.y);
        float zr = ur[pb], zi = ui[pb];
        ur[pb] = Ar * zr - Ai * zi + Br * arq + Bi * aiq;
        ui[pb] = Ar * zi + Ai * zr + Bi * arq - Br * aiq;
      }
    }
  }
  __builtin_amdgcn_sched_barrier(0);

  #pragma unroll
  for (int s = 0; s < 4; ++s) {
    const int hh = 1 << s;
    #pragma unroll
    for (int i = 0; i < 16; ++i) if (!(i & hh)) {
      const int tw = (i & (hh - 1)) * (16 / hh);
      float tr2 = ur[i + hh] * CW16[tw] - ui[i + hh] * SW16[tw];
      float ti2 = ui[i + hh] * CW16[tw] + ur[i + hh] * SW16[tw];
      ur[i + hh] = ur[i] - tr2; ui[i + hh] = ui[i] - ti2;
      ur[i] += tr2; ui[i] += ti2;
    }
  }
  #pragma unroll
  for (int j = 1; j < 16; ++j) {
    const float rev = (float)(j * kap) * (1.0f / 1024.0f);
    const float sn = hsin(rev), cs = hcos(rev);
    float t = ur[j] * cs - ui[j] * sn;
    ui[j] = ui[j] * cs + ur[j] * sn;
    ur[j] = t;
  }
  #pragma unroll
  for (int s = 0; s < 6; ++s) {
    const int hh = 1 << s;
    const int j = lane & (hh - 1);
    const float rev = (float)j * (0.5f / (float)hh);
    const bool hi = (lane & hh) != 0;
    const float c  = hi ? hcos(rev) : 1.0f;
    const float sv = hi ? hsin(rev) : 0.0f;
    const float sgn = hi ? -1.0f : 1.0f;
    #pragma unroll
    for (int r = 0; r < 16; ++r) {
      float vr = fmaf(-ui[r], sv, ur[r] * c);
      float vi = fmaf(ur[r], sv, ui[r] * c);
      float pvr = __shfl_xor(vr, hh, 64);
      float pvi = __shfl_xor(vi, hh, 64);
      ur[r] = fmaf(sgn, vr, pvr);
      ui[r] = fmaf(sgn, vi, pvi);
    }
  }

  uint4* dst = (uint4*)(yT + col * 2048) + lane * 4;
  #pragma unroll
  for (int g = 0; g < 4; ++g) {
    uint4 o;
    o.x = pack2bf(ur[4 * g + 0], ui[4 * g + 0]);
    o.y = pack2bf(ur[4 * g + 1], ui[4 * g + 1]);
    o.z = pack2bf(ur[4 * g + 2], ui[4 * g + 2]);
    o.w = pack2bf(ur[4 * g + 3], ui[4 * g + 3]);
    dst[g] = o;
  }
}

// ---------- fallback (R3-proven): FFT-2048 reading x directly via LDS staging ----------
__global__ __attribute__((amdgpu_flat_work_group_size(512, 512)))
__attribute__((amdgpu_waves_per_eu(2, 4)))
void fft_gate_k(const float* __restrict__ x,
                const unsigned int* __restrict__ gt,
                unsigned short* __restrict__ y) {
  __shared__ float lds[8 * 516];
  const int tid = threadIdx.x;
  const int w = tid >> 6;
  const int lane = tid & 63;
  const int bid = blockIdx.x;
  const int swz = (bid & 7) * 256 + (bid >> 3);
  const int h0 = (swz & 255) << 3;
  const int b = swz >> 8;
  const int hh = tid & 7, srow = tid >> 3;

  float ur[32], ui[32];
  const size_t xbase = ((size_t)b * 2048) * 2048 + h0;

  for (int c = 0; c < 4; ++c) {
    #pragma unroll
    for (int q = 0; q < 8; ++q) {
      int soff = q * 64 + srow;
      float v = x[xbase + (size_t)(c * 512 + soff) * 2048 + hh];
      lds[hh * 516 + (soff ^ ((soff >> 5) & 15))] = v;
    }
    __syncthreads();
    if ((lane >> 4) == c) {
      const int li = lane & 15;
      #pragma unroll
      for (int j = 0; j < 32; ++j) {
        ur[j] = lds[w * 516 + ((32 * li + j) ^ li)];
        ui[j] = 0.f;
      }
    }
    __syncthreads();
  }

  fwd_core(ur, ui, lane);
  {
    const int kap = bitrev6(lane);
    const unsigned int* grow = gt + (size_t)(h0 + w) * 2048;
    #pragma unroll
    for (int p = 0; p < 32; ++p) {
      unsigned int g = grow[(BR5[p] << 6) + kap];
      float gre = bflo(g), gim = bfhi(g);
      float t = ur[p] * gre - ui[p] * gim;
      ui[p] = ur[p] * gim + ui[p] * gre;
      ur[p] = t;
    }
  }
  inv_core(ur, ui, lane);

  for (int c = 0; c < 4; ++c) {
    if ((lane >> 4) == c) {
      const int li = lane & 15;
      #pragma unroll
      for (int r = 0; r < 32; ++r)
        lds[w * 516 + ((32 * li + r) ^ li)] = ur[r];
    }
    __syncthreads();
    #pragma unroll
    for (int q = 0; q < 8; ++q) {
      int soff = q * 64 + srow;
      float v = lds[hh * 516 + (soff ^ ((soff >> 5) & 15))];
      y[xbase + (size_t)(c * 512 + soff) * 2048 + hh] = f2bf(v);
    }
    __syncthreads();
  }
}

// ---------- GEMM fallback: m97-style 128x128 tile ----------
__global__ __launch_bounds__(256) void gemm_k(const unsigned short* __restrict__ A,
                                              const unsigned short* __restrict__ Bw,
                                              const float* __restrict__ bias,
                                              float* __restrict__ C) {
  __shared__ unsigned short sA[128 * 32];
  __shared__ unsigned short sB[128 * 32];
  const int tid = threadIdx.x;
  const int nwg = gridDim.x;
  const int cpx = nwg >> 3;
  const int bid = blockIdx.x;
  const int swz = (bid & 7) * cpx + (bid >> 3);
  const int bm = swz >> 4, bn = swz & 15;
  const int m0 = bm << 7, n0 = bn << 7;
  const int w = tid >> 6, lane = tid & 63;
  const int arow = tid >> 2, koff = (tid & 3) << 3;
  const unsigned short* gA = A + (size_t)(m0 + arow) * 2048 + koff;
  const unsigned short* gB = Bw + (size_t)(n0 + arow) * 2048 + koff;
  char* sAb = (char*)sA + w * 1024;
  char* sBb = (char*)sB + w * 1024;

  f32x4 acc[4][4];
  #pragma unroll
  for (int i = 0; i < 4; ++i)
    #pragma unroll
    for (int j = 0; j < 4; ++j) acc[i][j] = (f32x4){0.f, 0.f, 0.f, 0.f};

  const int wr = w >> 1, wc = w & 1;
  const int row16 = lane & 15, kb = lane >> 4;

  for (int k0 = 0; k0 < 2048; k0 += 32) {
    glds16(gA + k0, sAb);
    glds16(gA + 64 * 2048 + k0, sAb + 4096);
    glds16(gB + k0, sBb);
    glds16(gB + 64 * 2048 + k0, sBb + 4096);
    __syncthreads();
    bf16x8 af[4], bfr[4];
    #pragma unroll
    for (int i = 0; i < 4; ++i) {
      int r = (wr << 6) + (i << 4) + row16;
      af[i] = *(const bf16x8*)(sA + r * 32 + (kb << 3));
    }
    #pragma unroll
    for (int j2 = 0; j2 < 4; ++j2) {
      int r = (wc << 6) + (j2 << 4) + row16;
      bfr[j2] = *(const bf16x8*)(sB + r * 32 + (kb << 3));
    }
    #pragma unroll
    for (int i = 0; i < 4; ++i)
      #pragma unroll
      for (int j2 = 0; j2 < 4; ++j2)
        acc[i][j2] = __builtin_amdgcn_mfma_f32_16x16x32_bf16(af[i], bfr[j2], acc[i][j2], 0, 0, 0);
    __syncthreads();
  }

  const int rq = lane >> 4;
  #pragma unroll
  for (int j2 = 0; j2 < 4; ++j2) {
    int oc = n0 + (wc << 6) + (j2 << 4) + row16;
    float bj = bias[oc];
    #pragma unroll
    for (int i = 0; i < 4; ++i) {
      int mr = m0 + (wr << 6) + (i << 4) + (rq << 2);
      #pragma unroll
      for (int q = 0; q < 4; ++q)
        C[(size_t)(mr + q) * 2048 + oc] = acc[i][j2][q] + bj;
    }
  }
}

// ---------- GEMM main: 256x256 tile, 4-stage pipeline, 2-phase K-step + setprio ----------
// (R13-verified: 142 µs, MfmaUtil 41.7%. R16's 128x256/4-wave variant regressed
// to 232 µs — barrier amortization of the 8-wave tile beats cross-block TLP.)
__global__ __launch_bounds__(512) void gemm8_k(const unsigned short* __restrict__ A,
                                               const unsigned short* __restrict__ Bw,
                                               const float* __restrict__ bias,
                                               float* __restrict__ C) {
  extern __shared__ char lds[];   // 4 x (A 16KB + B 16KB) = 128 KiB
  const int tid = threadIdx.x;
  const int w = tid >> 6, lane = tid & 63;
  const int bid = blockIdx.x;
  const int swz = (bid & 7) * 64 + (bid >> 3);   // 512 wgs, 8 XCDs, bijective
  const int m0 = (swz >> 3) << 8;
  const int n0 = (swz & 7) << 8;
  const int wr = w >> 2, wc = w & 3;
  const int row16 = lane & 15, kb = lane >> 4;

  const int lr = lane >> 2, ls = lane & 3;
  const int r0 = (w << 5) + lr, r1 = r0 + 16;
  const unsigned short* pA0 = A  + (size_t)(m0 + r0) * 2048 + ((ls ^ ((r0 >> 1) & 3)) << 3);
  const unsigned short* pA1 = A  + (size_t)(m0 + r1) * 2048 + ((ls ^ ((r1 >> 1) & 3)) << 3);
  const unsigned short* pB0 = Bw + (size_t)(n0 + r0) * 2048 + ((ls ^ ((r0 >> 1) & 3)) << 3);
  const unsigned short* pB1 = Bw + (size_t)(n0 + r1) * 2048 + ((ls ^ ((r1 >> 1) & 3)) << 3);
  const int dW = w << 11;

  f32x4 acc[8][4];
  #pragma unroll
  for (int i = 0; i < 8; ++i)
    #pragma unroll
    for (int j = 0; j < 4; ++j) acc[i][j] = (f32x4){0.f, 0.f, 0.f, 0.f};

  auto STAGE_A = [&](int t) {
    char* base = lds + ((t & 3) << 15);
    const int k0 = t << 5;
    glds16(pA0 + k0, base + dW);
    glds16(pA1 + k0, base + dW + 1024);
  };
  auto STAGE_B = [&](int t) {
    char* base = lds + ((t & 3) << 15);
    const int k0 = t << 5;
    glds16(pB0 + k0, base + 16384 + dW);
    glds16(pB1 + k0, base + 16384 + dW + 1024);
  };
  auto LDA4 = [&](const char* base, int i0, bf16x8 (&af)[4]) {
    #pragma unroll
    for (int i = 0; i < 4; ++i) {
      const int r = (wr << 7) + ((i0 + i) << 4) + row16;
      af[i] = *(const bf16x8*)(base + (r << 6) + ((kb ^ ((r >> 1) & 3)) << 4));
    }
  };
  auto LDB4 = [&](const char* base, bf16x8 (&bfr)[4]) {
    #pragma unroll
    for (int j = 0; j < 4; ++j) {
      const int r = (wc << 6) + (j << 4) + row16;
      bfr[j] = *(const bf16x8*)(base + 16384 + (r << 6) + ((kb ^ ((r >> 1) & 3)) << 4));
    }
  };
  auto MM16 = [&](const bf16x8 (&af)[4], const bf16x8 (&bfr)[4], int i0) {
    #pragma unroll
    for (int i = 0; i < 4; ++i)
      #pragma unroll
      for (int j = 0; j < 4; ++j)
        acc[i0 + i][j] = __builtin_amdgcn_mfma_f32_16x16x32_bf16(af[i], bfr[j], acc[i0 + i][j], 0, 0, 0);
  };
  auto COMPUTE = [&](int t) {
    const char* base = lds + ((t & 3) << 15);
    bf16x8 af[4], af2[4], bfr[4];
    LDA4(base, 0, af); LDA4(base, 4, af2); LDB4(base, bfr);
    MM16(af, bfr, 0); MM16(af2, bfr, 4);
  };

  STAGE_A(0); STAGE_B(0); STAGE_A(1); STAGE_B(1); STAGE_A(2); STAGE_B(2);
  asm volatile("s_waitcnt vmcnt(8)" ::: "memory");
  __builtin_amdgcn_s_barrier();
  __builtin_amdgcn_sched_barrier(0);

  for (int t = 0; t < 61; ++t) {
    const char* base = lds + ((t & 3) << 15);
    bf16x8 af[4], bfr[4];
    LDA4(base, 0, af);
    LDB4(base, bfr);
    STAGE_A(t + 3);
    asm volatile("s_waitcnt lgkmcnt(0)" ::: "memory");
    __builtin_amdgcn_sched_barrier(0);
    __builtin_amdgcn_s_setprio(1);
    MM16(af, bfr, 0);
    __builtin_amdgcn_s_setprio(0);
    __builtin_amdgcn_s_barrier();
    bf16x8 af2[4];
    LDA4(base, 4, af2);
    STAGE_B(t + 3);
    asm volatile("s_waitcnt lgkmcnt(0)" ::: "memory");
    __builtin_amdgcn_sched_barrier(0);
    __builtin_amdgcn_s_setprio(1);
    MM16(af2, bfr, 4);
    __builtin_amdgcn_s_setprio(0);
    asm volatile("s_waitcnt vmcnt(8)" ::: "memory");
    __builtin_amdgcn_s_barrier();
    __builtin_amdgcn_sched_barrier(0);
  }
  COMPUTE(61);
  asm volatile("s_waitcnt vmcnt(4)" ::: "memory");
  __builtin_amdgcn_s_barrier();
  __builtin_amdgcn_sched_barrier(0);
  COMPUTE(62);
  asm volatile("s_waitcnt vmcnt(0)" ::: "memory");
  __builtin_amdgcn_s_barrier();
  __builtin_amdgcn_sched_barrier(0);
  COMPUTE(63);

  const int rq = lane >> 4;
  #pragma unroll
  for (int j = 0; j < 4; ++j) {
    const int oc = n0 + (wc << 6) + (j << 4) + row16;
    const float bj = bias[oc];
    #pragma unroll
    for (int i = 0; i < 8; ++i) {
      const int mr = m0 + (wr << 7) + (i << 4) + (rq << 2);
      #pragma unroll
      for (int q = 0; q < 4; ++q)
        C[(size_t)(mr + q) * 2048 + oc] = acc[i][j][q] + bj;
    }
  }
}

extern "C" void kernel_launch(void* const* d_in, const int* in_sizes, int n_in,
                              void* d_out, int out_size, void* d_ws, size_t ws_size,
                              hipStream_t stream) {
  const float* x  = (const float*)d_in[0];
  const float* gr = (const float*)d_in[1];
  const float* gi = (const float*)d_in[2];
  const float* W  = (const float*)d_in[3];
  const float* bs = (const float*)d_in[4];
  float* out = (float*)d_out;

  char* ws = (char*)d_ws;
  unsigned short* yb = (unsigned short*)ws;                          // 64 MB  y bf16 [b,s,h]
  unsigned short* Wb = (unsigned short*)(ws + (64ull << 20));        // 8 MB   W bf16
  unsigned int*   gt = (unsigned int*)(ws + (72ull << 20));          // 16 MB  gate (fallback)
  uint2*          ab = (uint2*)(ws + (72ull << 20));                 // 16 MB  A/B table (fast)
  unsigned short* xT = (unsigned short*)(ws + (88ull << 20));        // 64 MB  x transposed BF16 [b,h,s]
  unsigned short* yT = (unsigned short*)(ws + (216ull << 20));       // 64 MB  y transposed [b,h,s]
  const bool fast = ws_size >= (280ull << 20);

  hipLaunchKernelGGL(wconv_k, dim3(4096), dim3(256), 0, stream, W, Wb);
  if (fast) {
    hipLaunchKernelGGL(gate_ab_k, dim3(32, 64), dim3(256), 0, stream, gr, gi, ab);
    hipLaunchKernelGGL(xtrans_k, dim3(32, 32, 8), dim3(256), 0, stream, x, xT);
    hipLaunchKernelGGL(fftr_k, dim3(4096), dim3(256), 0, stream, xT, ab, yT);
    hipLaunchKernelGGL(ytrans_k, dim3(32, 32, 8), dim3(256), 0, stream, yT, yb);
  } else {
    hipLaunchKernelGGL(gate_pack_k, dim3(64, 64), dim3(256), 0, stream, gr, gi, gt);
    hipLaunchKernelGGL(fft_gate_k, dim3(2048), dim3(512), 0, stream, x, gt, yb);
  }

  const bool big = hipFuncSetAttribute((const void*)gemm8_k,
                                       hipFuncAttributeMaxDynamicSharedMemorySize,
                                       131072) == hipSuccess;
  if (big) {
    hipLaunchKernelGGL(gemm8_k, dim3(512), dim3(512), 131072, stream, yb, Wb, bs, out);
  } else {
    hipLaunchKernelGGL(gemm_k, dim3(2048), dim3(256), 0, stream, yb, Wb, bs, out);
  }
}